// Round 3
// baseline (545.058 us; speedup 1.0000x reference)
//
#include <hip/hip_runtime.h>

// ExodusNet: per-timestep dense (32->1) + ExpLeak scan + LIF (SingleSpike,
// MembraneSubtract, norm_input=True). B=32768, F=32, T=100.
// Memory-bound: 419 MB read / 13 MB write -> ~69 us kernel roofline at 6.3 TB/s.
//
// PRECISION CONTRACT (round 1 post-mortem — DO NOT CHANGE THE ARITHMETIC):
// output is binary spikes; any near-threshold flip costs absmax=1.0. The
// harness ref (ref=np) is fp32. Bit-exact parity requires:
//   - dot over f: sequential f=0..31, fp32, separate mul/add rounding
//   - scans: fp32, mul-then-add, NO fma contraction (contract off)
//   - ALPHA = (float)exp(-0.1); OMA = (float)(1.0 - exp(-0.1)) [f64 -> f32]
// Round 2 verified absmax = 0.0 with exactly this ordering.
//
// Round 3 change: NB 64->32 (grid 512->1024 blocks, 4 blocks/CU instead of 2,
// 16 waves/CU) + __launch_bounds__(256,4) to cap VGPR<=128. Kernel was
// latency/occupancy-bound (~150 us vs 69 us roofline at 8 waves/CU).

constexpr int T_STEPS = 100;
constexpr int F_IN    = 32;
constexpr int NB      = 32;            // batches per block
constexpr int BLOCK   = 256;
constexpr int QT      = T_STEPS / 4;   // 25 float4 per time row
constexpr int ROWF    = T_STEPS + 4;   // 104 floats/row: float4-aligned pad,
                                       // breaks the 100-float stride pattern

__global__ __launch_bounds__(BLOCK, 4) void snn_fused(
    const float* __restrict__ x,   // (B, 32, 100)
    const float* __restrict__ w,   // (1, 32)
    float* __restrict__ out)       // (B, 1, 100)
{
#pragma clang fp contract(off)
    __shared__ float sw[NB * ROWF];   // 13.3 KB: weighted currents

    const int tid = threadIdx.x;
    const long long b0 = (long long)blockIdx.x * NB;

    // Weights: uniform address -> compiler emits scalar loads.
    float wf[F_IN];
#pragma unroll
    for (int f = 0; f < F_IN; ++f) wf[f] = w[f];

    // ---- Phase 1: weighted[nb][t] = sum_f x[b0+nb, f, t] * w[f] ----
    // fp32, sequential over f, each term separately rounded (no fma).
    // Task = (nb, j): one float4 of t. Lanes sweep consecutive j -> 400-B
    // coalesced runs per f-slice.
#pragma unroll
    for (int i = tid; i < NB * QT; i += BLOCK) {   // 800 tasks, 3-4 per thread
        const int nb = i / QT;
        const int j  = i - nb * QT;
        const float* xb = x + (b0 + nb) * (long long)(F_IN * T_STEPS) + 4 * j;
        float a0 = 0.0f, a1 = 0.0f, a2 = 0.0f, a3 = 0.0f;
#pragma unroll
        for (int f = 0; f < F_IN; ++f) {
            const float4 xv = *(const float4*)(xb + f * T_STEPS);
            a0 = a0 + xv.x * wf[f];
            a1 = a1 + xv.y * wf[f];
            a2 = a2 + xv.z * wf[f];
            a3 = a3 + xv.w * wf[f];
        }
        float4* dst = (float4*)(sw + nb * ROWF + 4 * j);
        *dst = make_float4(a0, a1, a2, a3);
    }
    __syncthreads();

    // ---- Phase 2: fused ExpLeak + LIF sequential scan, one thread/batch ----
    // syn[t] = a*syn + i[t];  v[t] = a*v + (1-a)*syn[t];
    // s = (v >= 1);  v -= s  (MembraneSubtract, THR=1). All fp32, no fma.
    if (tid < NB) {
        const double ALPHA64 = 0.90483741803595957316;  // exp(-1/10) in f64
        const float  A   = (float)ALPHA64;
        const float  OMA = (float)(1.0 - ALPHA64);      // f64 sub, then f32 cast
        float syn = 0.0f, v = 0.0f;
        const float* row = sw + tid * ROWF;
        float4* op = (float4*)(out + (b0 + tid) * (long long)T_STEPS);
#pragma unroll
        for (int q = 0; q < QT; ++q) {
            float4 s4;
            float* sp = (float*)&s4;
#pragma unroll
            for (int k = 0; k < 4; ++k) {
                syn = (A * syn) + row[4 * q + k];
                v   = (A * v) + (OMA * syn);
                const float s = (v >= 1.0f) ? 1.0f : 0.0f;
                v = v - s;
                sp[k] = s;
            }
            op[q] = s4;   // per-thread contiguous, 16-B aligned (100%4==0)
        }
    }
}

extern "C" void kernel_launch(void* const* d_in, const int* in_sizes, int n_in,
                              void* d_out, int out_size, void* d_ws, size_t ws_size,
                              hipStream_t stream) {
    const float* x  = (const float*)d_in[0];
    const float* w  = (const float*)d_in[1];
    float* out      = (float*)d_out;
    const int B       = in_sizes[0] / (F_IN * T_STEPS);  // 32768
    const int nblocks = B / NB;                          // 1024
    snn_fused<<<nblocks, BLOCK, 0, stream>>>(x, w, out);
}

// Round 4
// 519.096 us; speedup vs baseline: 1.0500x; 1.0500x over previous
//
#include <hip/hip_runtime.h>

// ExodusNet: per-timestep dense (32->1) + ExpLeak scan + LIF (SingleSpike,
// MembraneSubtract, norm_input=True). B=32768, F=32, T=100.
// Kernel roofline: 419 MB read + 13 MB write -> ~69 us at 6.3 TB/s.
// Bench dur_us also contains harness restore/poison (~390 us fixed).
//
// PRECISION CONTRACT (round 1 post-mortem — DO NOT CHANGE THE ARITHMETIC):
// output is binary spikes; a near-threshold flip costs absmax=1.0. ref=np is
// fp32. Bit-exact parity requires: dot sequential f=0..31 in fp32 with
// separate mul/add rounding (contract off); scans fp32 mul-then-add no-fma;
// ALPHA=(float)exp(-0.1), OMA=(float)(1.0-exp(-0.1)). Rounds 2-3: absmax=0.0.
//
// Round 4 change (load-pattern hypothesis): rounds 2/3 used 400-B-run loads
// (~3 discontiguous runs per wave instruction) and both landed at the same
// dur — occupancy change was a no-op, so the kernel is pattern-limited, not
// occupancy-limited. Now: stage each block's contiguous 51.2 KB x-slab into
// LDS with perfectly lane-linear 1-KB-per-instruction float4 nontemporal
// loads (m13 copy pattern), compute the exact dense from LDS, then scan.
// NB=4, BLOCK=128, LDS 52.9 KB -> 3 blocks/CU so per-block barrier drains
// overlap across resident blocks.

typedef float vf4 __attribute__((ext_vector_type(4)));

constexpr int T_STEPS = 100;
constexpr int F_IN    = 32;
constexpr int NB      = 4;                    // batch rows per block
constexpr int BLOCK   = 128;
constexpr int QT      = T_STEPS / 4;          // 25 float4 per time row
constexpr int ROWF    = T_STEPS + 4;          // 104: padded currents row
constexpr int SLABF   = NB * F_IN * T_STEPS;  // 12800 floats = 51200 B
constexpr int CHUNKS  = SLABF / (4 * BLOCK);  // 25 float4 loads per thread

__global__ __launch_bounds__(BLOCK) void snn_fused(
    const float* __restrict__ x,   // (B, 32, 100)
    const float* __restrict__ w,   // (1, 32)
    float* __restrict__ out)       // (B, 1, 100)
{
#pragma clang fp contract(off)
    __shared__ float xs[SLABF];        // 51.2 KB: verbatim x slab (bit-exact)
    __shared__ float cur[NB * ROWF];   // 1.7 KB: weighted currents

    const int tid = threadIdx.x;
    const long long blk = blockIdx.x;
    const float* slab = x + blk * (long long)SLABF;

    // ---- Phase A: stage slab -> LDS, perfectly coalesced ----
    // float4 #(c*128+tid): each wave instruction covers an aligned,
    // contiguous 1 KB (m13 pattern). x is read exactly once chip-wide ->
    // nontemporal. All 25 loads hoisted before the LDS writes for max MLP.
    vf4 v[CHUNKS];
#pragma unroll
    for (int c = 0; c < CHUNKS; ++c)
        v[c] = __builtin_nontemporal_load((const vf4*)slab + c * BLOCK + tid);
#pragma unroll
    for (int c = 0; c < CHUNKS; ++c)
        ((vf4*)xs)[c * BLOCK + tid] = v[c];

    // Weights: uniform address -> scalar loads.
    float wf[F_IN];
#pragma unroll
    for (int f = 0; f < F_IN; ++f) wf[f] = w[f];

    __syncthreads();

    // ---- Phase B: cur[nb][t] = sum_f xs[nb, f, t] * w[f] ----
    // fp32, sequential over f, separate mul/add rounding (no fma).
    // One task per thread: (nb, j), threads 100..127 idle.
    if (tid < NB * QT) {
        const int nb = tid / QT;
        const int j  = tid - nb * QT;
        const float* xr = xs + nb * (F_IN * T_STEPS) + 4 * j;
        float a0 = 0.0f, a1 = 0.0f, a2 = 0.0f, a3 = 0.0f;
#pragma unroll
        for (int f = 0; f < F_IN; ++f) {
            const vf4 xv = *(const vf4*)(xr + f * T_STEPS);  // ds_read_b128
            a0 = a0 + xv.x * wf[f];
            a1 = a1 + xv.y * wf[f];
            a2 = a2 + xv.z * wf[f];
            a3 = a3 + xv.w * wf[f];
        }
        vf4* dst = (vf4*)(cur + nb * ROWF + 4 * j);
        *dst = vf4{a0, a1, a2, a3};
    }
    __syncthreads();

    // ---- Phase C: fused ExpLeak + LIF scan, one thread per batch row ----
    // syn[t] = A*syn + i[t];  v[t] = A*v + OMA*syn;
    // s = (v >= 1);  v -= s  (MembraneSubtract, THR=1). All fp32, no fma.
    if (tid < NB) {
        const double ALPHA64 = 0.90483741803595957316;  // exp(-1/10) in f64
        const float  A   = (float)ALPHA64;
        const float  OMA = (float)(1.0 - ALPHA64);      // f64 sub -> f32 cast
        float syn = 0.0f, vmem = 0.0f;
        const float* row = cur + tid * ROWF;
        vf4* op = (vf4*)(out + (blk * NB + tid) * (long long)T_STEPS);
#pragma unroll
        for (int q = 0; q < QT; ++q) {
            vf4 s4;
#pragma unroll
            for (int k = 0; k < 4; ++k) {
                syn  = (A * syn) + row[4 * q + k];
                vmem = (A * vmem) + (OMA * syn);
                const float s = (vmem >= 1.0f) ? 1.0f : 0.0f;
                vmem = vmem - s;
                s4[k] = s;
            }
            op[q] = s4;   // per-thread contiguous, 16-B aligned (400 B rows)
        }
    }
}

extern "C" void kernel_launch(void* const* d_in, const int* in_sizes, int n_in,
                              void* d_out, int out_size, void* d_ws, size_t ws_size,
                              hipStream_t stream) {
    const float* x  = (const float*)d_in[0];
    const float* w  = (const float*)d_in[1];
    float* out      = (float*)d_out;
    const int B       = in_sizes[0] / (F_IN * T_STEPS);  // 32768
    const int nblocks = B / NB;                          // 8192
    snn_fused<<<nblocks, BLOCK, 0, stream>>>(x, w, out);
}